// Round 6
// baseline (231.146 us; speedup 1.0000x reference)
//
#include <hip/hip_runtime.h>
#include <hip/hip_bf16.h>

// RandScatter with a CONSTANT score matrix:
//   score.argmax(axis=1) = [0, 1, 1, 1]
//   path 0 <- token 0            -> out chunk 0 = inputs[0:1, :]
//   path 1 <- tokens 1, 2, 3     -> out chunk 1 = inputs[1:4, :]
// Concatenated flat output = tokens [0,1,2,3] in order = the input, verbatim.
// The op is a 128 MiB fp32 D2D copy, memory-bound.
//
// Round 2 lesson: hipMemcpyAsync under graph capture ran on the SDMA/blit
// path at only ~1.2 TB/s (222 us). A plain float4 grid-stride compute-kernel
// copy reaches the ~6.3 TB/s kernel ceiling (m13 pattern).

__global__ __launch_bounds__(256) void copy_f4_kernel(
    const float4* __restrict__ src, float4* __restrict__ dst, long n4) {
    long i = (long)blockIdx.x * blockDim.x + threadIdx.x;
    long stride = (long)gridDim.x * blockDim.x;
    for (; i < n4; i += stride) dst[i] = src[i];
}

extern "C" void kernel_launch(void* const* d_in, const int* in_sizes, int n_in,
                              void* d_out, int out_size, void* d_ws, size_t ws_size,
                              hipStream_t stream) {
    (void)n_in; (void)d_ws; (void)ws_size; (void)in_sizes;
    const float4* in = (const float4*)d_in[0];
    float4* out = (float4*)d_out;
    // out_size = 4 * 8388608 fp32 = 33554432 elements = 8388608 float4s.
    long n4 = (long)out_size / 4;
    const int block = 256;
    const int grid = 2048;  // 256 CUs x 8 blocks/CU, grid-stride covers the rest
    copy_f4_kernel<<<grid, block, 0, stream>>>(in, out, n4);
}